// Round 9
// baseline (63.128 us; speedup 1.0000x reference)
//
#include <hip/hip_runtime.h>
#include <hip/hip_bf16.h>

#define B_   4
#define C_   64
#define N_   16384
#define K_   20
#define S_   10
#define OUT_ 64
#define CH_  128
#define ROWS_ (B_ * N_)
#define RST_ 16   // stats replicas

typedef __attribute__((ext_vector_type(4))) float  f32x4;
typedef __attribute__((ext_vector_type(8))) __bf16 bf16x8;
typedef __attribute__((ext_vector_type(4))) __bf16 bf16x4;
typedef __attribute__((ext_vector_type(4))) unsigned short u16x4;
typedef __attribute__((ext_vector_type(8))) unsigned short u16x8;

__device__ inline float bf2f(unsigned short u) {
  union { unsigned int i; float f; } x; x.i = ((unsigned int)u) << 16; return x.f;
}

// ---- fused: transpose -> bf16 xt | top-S sample | statsR zero | pw fragment prepack ----
__global__ __launch_bounds__(256) void k_prep(
    const float* __restrict__ x, __bf16* __restrict__ xt,
    const float* __restrict__ scores, const int* __restrict__ idxmat,
    int* __restrict__ sampled, float* __restrict__ statsR,
    const float* __restrict__ pw, __bf16* __restrict__ pwb2) {
  const int bid = blockIdx.x;
  const int t   = threadIdx.x;
  if (bid < 4096) {
    __shared__ float tile[32][33];   // [c_local][n_local]
    const int nt = bid & 511, ct = (bid >> 9) & 1, b = bid >> 10;
    const int n0 = nt * 32, c0 = ct * 32;
    const int tx = t & 31, ty = t >> 5;
#pragma unroll
    for (int k = 0; k < 32; k += 8)
      tile[ty + k][tx] = x[((size_t)(b * C_ + c0 + ty + k)) * N_ + n0 + tx];
    __syncthreads();
    const int nl = t >> 3;           // 0..31 (n)
    const int cb = (t & 7) * 4;      // 0..28 (c)
    bf16x4 p;
#pragma unroll
    for (int i = 0; i < 4; ++i) p[i] = (__bf16)tile[cb + i][nl];
    *(bf16x4*)&xt[((size_t)(b * N_ + n0 + nl)) * C_ + c0 + cb] = p;
  } else if (bid < 4352) {
    if (bid == 4096) {
#pragma unroll
      for (int i = 0; i < RST_; ++i) statsR[i * 256 + t] = 0.f;
    }
    const int j = (bid - 4096) * 256 + t;
    const float* sc = scores + (size_t)j * K_;
    const int*   id = idxmat + (size_t)j * K_;
    float sv[K_]; int iv[K_];
#pragma unroll
    for (int k = 0; k < K_; ++k) { sv[k] = sc[k]; iv[k] = id[k]; }
    int* outp = sampled + (size_t)j * S_;
#pragma unroll
    for (int k = 0; k < K_; ++k) {
      const float sk = sv[k];
      int rank = 0;
#pragma unroll
      for (int m = 0; m < K_; ++m)
        rank += ((sv[m] > sk) || (sv[m] == sk && m < k)) ? 1 : 0;
      if (rank < S_) outp[rank] = iv[k];
    }
  } else {
    // pack pw into per-lane MFMA B-fragment order:
    // entry e = ((og*2+ts)*4 + ks)*16 + col ; elem i = pw[16og+col][32ts+8ks+i] (d) / [64+...] (c)
#pragma unroll
    for (int pass = 0; pass < 2; ++pass) {
      const int e   = t + pass * 256;
      const int col = e & 15, ks = (e >> 4) & 3, ts = (e >> 6) & 1, og = (e >> 7) & 3;
      const float* src = pw + (size_t)(16 * og + col) * CH_ + 32 * ts + 8 * ks;
      bf16x8 dv, cv;
#pragma unroll
      for (int i = 0; i < 8; ++i) { dv[i] = (__bf16)src[i]; cv[i] = (__bf16)src[C_ + i]; }
      *(bf16x8*)&pwb2[e * 8]        = dv;
      *(bf16x8*)&pwb2[4096 + e * 8] = cv;
    }
  }
}

// ---------------- BN stats: gather, register accum, wave reduce, replicated atomics ----------------
__global__ __launch_bounds__(256, 4) void k_stats(const __bf16* __restrict__ xt,
                                                  const int* __restrict__ sampled,
                                                  float* __restrict__ statsR) {
  const int t    = threadIdx.x;
  const int lane = t & 63;
  const int w    = t >> 6;
  const int r    = t >> 4;
  const int q    = t & 15;
  const int j0   = blockIdx.x * 32;
  const int jA   = j0 + r;
  const int jB   = j0 + 16 + r;

  int ia[S_], ib[S_];
  const int* spA = sampled + (size_t)jA * S_;
  const int* spB = sampled + (size_t)jB * S_;
#pragma unroll
  for (int s = 0; s < S_; ++s) { ia[s] = spA[s]; ib[s] = spB[s]; }

  u16x4 cA = *(const u16x4*)&xt[jA * C_ + 4 * q];
  u16x4 cB = *(const u16x4*)&xt[jB * C_ + 4 * q];

  u16x4 vA[S_], vB[S_];
#pragma unroll
  for (int s = 0; s < S_; ++s) {
    vA[s] = *(const u16x4*)&xt[ia[s] * C_ + 4 * q];
    vB[s] = *(const u16x4*)&xt[ib[s] * C_ + 4 * q];
  }
  __builtin_amdgcn_sched_barrier(0);

  f32x4 sd = {0,0,0,0}, qd = {0,0,0,0}, sc = {0,0,0,0}, qc = {0,0,0,0};
  float cenA[4], cenB[4];
#pragma unroll
  for (int i = 0; i < 4; ++i) {
    cenA[i] = bf2f(cA[i]); cenB[i] = bf2f(cB[i]);
    sc[i] += cenA[i] + cenB[i];
    qc[i] += cenA[i] * cenA[i] + cenB[i] * cenB[i];
  }
#pragma unroll
  for (int s = 0; s < S_; ++s) {
#pragma unroll
    for (int i = 0; i < 4; ++i) {
      const float dA = bf2f(vA[s][i]) - cenA[i];
      const float dB = bf2f(vB[s][i]) - cenB[i];
      sd[i] += dA + dB;
      qd[i] += dA * dA + dB * dB;
    }
  }

#pragma unroll
  for (int i = 0; i < 4; ++i) {
    sd[i] += __shfl_xor(sd[i], 16); sd[i] += __shfl_xor(sd[i], 32);
    qd[i] += __shfl_xor(qd[i], 16); qd[i] += __shfl_xor(qd[i], 32);
    sc[i] += __shfl_xor(sc[i], 16); sc[i] += __shfl_xor(sc[i], 32);
    qc[i] += __shfl_xor(qc[i], 16); qc[i] += __shfl_xor(qc[i], 32);
  }

  __shared__ float sred[4][4][64];
  if (lane < 16) {
    *(f32x4*)&sred[0][w][4 * q] = sd;
    *(f32x4*)&sred[1][w][4 * q] = qd;
    *(f32x4*)&sred[2][w][4 * q] = sc;
    *(f32x4*)&sred[3][w][4 * q] = qc;
  }
  __syncthreads();
  if (t < 64) {
    float* dst = statsR + (blockIdx.x & (RST_ - 1)) * 256;
#pragma unroll
    for (int k = 0; k < 4; ++k) {
      const float v = sred[k][0][t] + sred[k][1][t] + sred[k][2][t] + sred[k][3][t];
      atomicAdd(&dst[k * 64 + t], v);
    }
  }
}

// ---------------- scale: redundant fold + prescale xd = A_d*x, actc = leaky(A_c*x+B_c) ----------------
__global__ __launch_bounds__(256) void k_scale(
    const float* __restrict__ statsR, const float* __restrict__ dww,
    const float* __restrict__ gamma, const float* __restrict__ beta,
    const __bf16* __restrict__ xt, __bf16* __restrict__ xd,
    __bf16* __restrict__ actc, float* __restrict__ AB) {
  __shared__ float sstat[256];
  __shared__ float abf[256];
  const int t = threadIdx.x;
  float sv = 0.f;
#pragma unroll
  for (int rr = 0; rr < RST_; ++rr) sv += statsR[rr * 256 + t];
  sstat[t] = sv;
  __syncthreads();
  if (t < CH_) {
    float mean_e, var_e;
    if (t < C_) {
      const float cnt = (float)ROWS_ * (float)S_;
      mean_e = sstat[t] / cnt; var_e = sstat[64 + t] / cnt - mean_e * mean_e;
    } else {
      const float cnt = (float)ROWS_;
      mean_e = sstat[128 + (t - C_)] / cnt; var_e = sstat[192 + (t - C_)] / cnt - mean_e * mean_e;
    }
    const float wg = dww[t], g = gamma[t];
    const float inv = rsqrtf(wg * wg * var_e + 1e-5f);
    abf[t]       = wg * g * inv;                       // A
    abf[CH_ + t] = beta[t] - wg * mean_e * inv * g;    // B
  }
  __syncthreads();
  if (blockIdx.x == 0) AB[t] = abf[t];

  const int g   = blockIdx.x * 256 + t;
  const int row = g >> 3;
  const int c8  = (g & 7) * 8;
  u16x8 xv = *(const u16x8*)&xt[(size_t)row * C_ + c8];
  bf16x8 xdv, acv;
#pragma unroll
  for (int i = 0; i < 8; ++i) {
    const int c = c8 + i;
    const float f = bf2f(xv[i]);
    xdv[i] = (__bf16)(abf[c] * f);
    const float tc = abf[C_ + c] * f + abf[CH_ + C_ + c];
    acv[i] = (__bf16)fmaxf(tc, 0.2f * tc);
  }
  *(bf16x8*)&xd[(size_t)row * C_ + c8]   = xdv;
  *(bf16x8*)&actc[(size_t)row * C_ + c8] = acv;
}

// ---------------- main: LDS-free fragment-aligned gather + act + MFMA + max over S ----------------
__global__ __launch_bounds__(256, 3) void k_main(
    const __bf16* __restrict__ xd, const __bf16* __restrict__ actc,
    const int* __restrict__ sampled, const float* __restrict__ AB,
    const __bf16* __restrict__ pwb2, float* __restrict__ out) {
  const int t   = threadIdx.x;
  const int l   = t & 63;
  const int w   = t >> 6;
  const int j0  = blockIdx.x * 64 + w * 16;    // wave's 16-row group
  const int b   = j0 / N_;
  const int n0  = j0 % N_;
  const int col = l & 15;                       // A row / D col
  const int ks  = l >> 4;                       // k-slice 0..3
  const int jr  = j0 + col;                     // this lane's data row
  const int cb  = 8 * ks;                       // channel base

  // ---- load phase ----
  int nb[S_];
  const int* sp = sampled + (size_t)jr * S_;
#pragma unroll
  for (int s = 0; s < S_; ++s) nb[s] = sp[s];

  u16x8 vd[S_][2];
#pragma unroll
  for (int s = 0; s < S_; ++s) {
    const __bf16* p = xd + (size_t)nb[s] * C_ + cb;
    vd[s][0] = *(const u16x8*)p;
    vd[s][1] = *(const u16x8*)(p + 32);
  }
  u16x8 cd0 = *(const u16x8*)(xd + (size_t)jr * C_ + cb);
  u16x8 cd1 = *(const u16x8*)(xd + (size_t)jr * C_ + cb + 32);

  f32x4 b0a = *(const f32x4*)&AB[CH_ + cb];
  f32x4 b0b = *(const f32x4*)&AB[CH_ + cb + 4];
  f32x4 b1a = *(const f32x4*)&AB[CH_ + 32 + cb];
  f32x4 b1b = *(const f32x4*)&AB[CH_ + 32 + cb + 4];

  bf16x8 bfd[2][4];
#pragma unroll
  for (int og = 0; og < 4; ++og)
#pragma unroll
    for (int ts = 0; ts < 2; ++ts)
      bfd[ts][og] = *(const bf16x8*)&pwb2[(((og * 2 + ts) * 4 + ks) * 16 + col) * 8];
  __builtin_amdgcn_sched_barrier(0);

  // cc = xd_central - B_d  (act = leaky(v - cc))
  float cc[16];
#pragma unroll
  for (int i = 0; i < 4; ++i) {
    cc[i]      = bf2f(cd0[i])     - b0a[i];
    cc[4 + i]  = bf2f(cd0[4 + i]) - b0b[i];
    cc[8 + i]  = bf2f(cd1[i])     - b1a[i];
    cc[12 + i] = bf2f(cd1[4 + i]) - b1b[i];
  }

  f32x4 rmax[4];
#pragma unroll
  for (int og = 0; og < 4; ++og)
    rmax[og][0] = rmax[og][1] = rmax[og][2] = rmax[og][3] = -__builtin_inff();

#pragma unroll
  for (int s = 0; s < S_; ++s) {
    bf16x8 a0, a1;
#pragma unroll
    for (int i = 0; i < 8; ++i) {
      const float f0 = bf2f(vd[s][0][i]) - cc[i];
      a0[i] = (__bf16)fmaxf(f0, 0.2f * f0);
      const float f1 = bf2f(vd[s][1][i]) - cc[8 + i];
      a1[i] = (__bf16)fmaxf(f1, 0.2f * f1);
    }
#pragma unroll
    for (int og = 0; og < 4; ++og) {
      f32x4 acc = {0.f, 0.f, 0.f, 0.f};
      acc = __builtin_amdgcn_mfma_f32_16x16x32_bf16(a0, bfd[0][og], acc, 0, 0, 0);
      acc = __builtin_amdgcn_mfma_f32_16x16x32_bf16(a1, bfd[1][og], acc, 0, 0, 0);
#pragma unroll
      for (int i = 0; i < 4; ++i) rmax[og][i] = fmaxf(rmax[og][i], acc[i]);
    }
  }
  __builtin_amdgcn_sched_barrier(0);

  // c-part (s-invariant): cacc = pw_c · actc
  bf16x8 ac0 = *(const bf16x8*)(actc + (size_t)jr * C_ + cb);
  bf16x8 ac1 = *(const bf16x8*)(actc + (size_t)jr * C_ + cb + 32);
#pragma unroll
  for (int og = 0; og < 4; ++og) {
    bf16x8 c0 = *(const bf16x8*)&pwb2[4096 + (((og * 2 + 0) * 4 + ks) * 16 + col) * 8];
    bf16x8 c1 = *(const bf16x8*)&pwb2[4096 + (((og * 2 + 1) * 4 + ks) * 16 + col) * 8];
    f32x4 cacc = {0.f, 0.f, 0.f, 0.f};
    cacc = __builtin_amdgcn_mfma_f32_16x16x32_bf16(ac0, c0, cacc, 0, 0, 0);
    cacc = __builtin_amdgcn_mfma_f32_16x16x32_bf16(ac1, c1, cacc, 0, 0, 0);
    f32x4 v;
#pragma unroll
    for (int i = 0; i < 4; ++i) v[i] = rmax[og][i] + cacc[i];
    // D layout: col = out channel 16og+col, rows = n0 + 4ks + i (contiguous in N)
    *(f32x4*)&out[(size_t)(b * OUT_ + 16 * og + col) * N_ + n0 + 4 * ks] = v;
  }
}

extern "C" void kernel_launch(void* const* d_in, const int* in_sizes, int n_in,
                              void* d_out, int out_size, void* d_ws, size_t ws_size,
                              hipStream_t stream) {
  const float* x      = (const float*)d_in[0];
  const int*   cif    = (const int*)  d_in[1];
  const float* scores = (const float*)d_in[2];
  const float* dww    = (const float*)d_in[3];
  const float* pw     = (const float*)d_in[4];
  const float* gamma  = (const float*)d_in[5];
  const float* beta   = (const float*)d_in[6];
  float* out = (float*)d_out;

  char* ws = (char*)d_ws;
  __bf16* xt      = (__bf16*)(ws);                    //  8,388,608 B
  int*    sampled = (int*)   (ws + 8388608);          //  2,621,440 B
  float*  statsR  = (float*) (ws + 11010048);         //     16,384 B
  float*  AB      = (float*) (ws + 11026432);         //      1,024 B
  __bf16* pwb2    = (__bf16*)(ws + 11027456);         //     16,384 B
  __bf16* xd      = (__bf16*)(ws + 11043840);         //  8,388,608 B
  __bf16* actc    = (__bf16*)(ws + 19432448);         //  8,388,608 B

  k_prep<<<4096 + 256 + 1, 256, 0, stream>>>(x, xt, scores, cif, sampled, statsR, pw, pwb2);
  k_stats<<<ROWS_ / 32, 256, 0, stream>>>(xt, sampled, statsR);
  k_scale<<<ROWS_ * C_ / 8 / 256, 256, 0, stream>>>(statsR, dww, gamma, beta, xt, xd, actc, AB);
  k_main<<<ROWS_ / 64, 256, 0, stream>>>(xd, actc, sampled, AB, pwb2, out);
}

// Round 10
// 59.561 us; speedup vs baseline: 1.0599x; 1.0599x over previous
//
#include <hip/hip_runtime.h>
#include <hip/hip_bf16.h>

#define B_   4
#define C_   64
#define N_   16384
#define K_   20
#define S_   10
#define OUT_ 64
#define CH_  128
#define ROWS_ (B_ * N_)
#define RST_ 16   // stats replicas

typedef __attribute__((ext_vector_type(4))) float  f32x4;
typedef __attribute__((ext_vector_type(8))) __bf16 bf16x8;
typedef __attribute__((ext_vector_type(4))) __bf16 bf16x4;
typedef __attribute__((ext_vector_type(4))) unsigned short u16x4;
typedef __attribute__((ext_vector_type(8))) unsigned short u16x8;

__device__ inline float bf2f(unsigned short u) {
  union { unsigned int i; float f; } x; x.i = ((unsigned int)u) << 16; return x.f;
}

// ---- fused: transpose -> bf16 xt | top-S sample | statsR zero | pw fragment prepack ----
__global__ __launch_bounds__(256) void k_prep(
    const float* __restrict__ x, __bf16* __restrict__ xt,
    const float* __restrict__ scores, const int* __restrict__ idxmat,
    int* __restrict__ sampled, float* __restrict__ statsR,
    const float* __restrict__ pw, __bf16* __restrict__ pwb2) {
  const int bid = blockIdx.x;
  const int t   = threadIdx.x;
  if (bid < 4096) {
    __shared__ float tile[32][33];   // [c_local][n_local]
    const int nt = bid & 511, ct = (bid >> 9) & 1, b = bid >> 10;
    const int n0 = nt * 32, c0 = ct * 32;
    const int tx = t & 31, ty = t >> 5;
#pragma unroll
    for (int k = 0; k < 32; k += 8)
      tile[ty + k][tx] = x[((size_t)(b * C_ + c0 + ty + k)) * N_ + n0 + tx];
    __syncthreads();
    const int nl = t >> 3;           // 0..31 (n)
    const int cb = (t & 7) * 4;      // 0..28 (c)
    bf16x4 p;
#pragma unroll
    for (int i = 0; i < 4; ++i) p[i] = (__bf16)tile[cb + i][nl];
    *(bf16x4*)&xt[((size_t)(b * N_ + n0 + nl)) * C_ + c0 + cb] = p;
  } else if (bid < 4352) {
    if (bid == 4096) {
#pragma unroll
      for (int i = 0; i < RST_; ++i) statsR[i * 256 + t] = 0.f;
    }
    const int j = (bid - 4096) * 256 + t;
    const float* sc = scores + (size_t)j * K_;
    const int*   id = idxmat + (size_t)j * K_;
    float sv[K_]; int iv[K_];
#pragma unroll
    for (int k = 0; k < K_; ++k) { sv[k] = sc[k]; iv[k] = id[k]; }
    int* outp = sampled + (size_t)j * S_;
#pragma unroll
    for (int k = 0; k < K_; ++k) {
      const float sk = sv[k];
      int rank = 0;
#pragma unroll
      for (int m = 0; m < K_; ++m)
        rank += ((sv[m] > sk) || (sv[m] == sk && m < k)) ? 1 : 0;
      if (rank < S_) outp[rank] = iv[k];
    }
  } else {
    // pack pw into per-lane MFMA B-fragment order:
    // entry e = ((og*2+ts)*4 + ks)*16 + col ; elem i = pw[16og+col][32ts+8ks+i] (d) / [64+...] (c)
#pragma unroll
    for (int pass = 0; pass < 2; ++pass) {
      const int e   = t + pass * 256;
      const int col = e & 15, ks = (e >> 4) & 3, ts = (e >> 6) & 1, og = (e >> 7) & 3;
      const float* src = pw + (size_t)(16 * og + col) * CH_ + 32 * ts + 8 * ks;
      bf16x8 dv, cv;
#pragma unroll
      for (int i = 0; i < 8; ++i) { dv[i] = (__bf16)src[i]; cv[i] = (__bf16)src[C_ + i]; }
      *(bf16x8*)&pwb2[e * 8]        = dv;
      *(bf16x8*)&pwb2[4096 + e * 8] = cv;
    }
  }
}

// ---------------- BN stats: gather, register accum, wave reduce, replicated atomics ----------------
__global__ __launch_bounds__(256, 4) void k_stats(const __bf16* __restrict__ xt,
                                                  const int* __restrict__ sampled,
                                                  float* __restrict__ statsR) {
  const int t    = threadIdx.x;
  const int lane = t & 63;
  const int w    = t >> 6;
  const int r    = t >> 4;
  const int q    = t & 15;
  const int j0   = blockIdx.x * 32;
  const int jA   = j0 + r;
  const int jB   = j0 + 16 + r;

  int ia[S_], ib[S_];
  const int* spA = sampled + (size_t)jA * S_;
  const int* spB = sampled + (size_t)jB * S_;
#pragma unroll
  for (int s = 0; s < S_; ++s) { ia[s] = spA[s]; ib[s] = spB[s]; }

  u16x4 cA = *(const u16x4*)&xt[jA * C_ + 4 * q];
  u16x4 cB = *(const u16x4*)&xt[jB * C_ + 4 * q];

  u16x4 vA[S_], vB[S_];
#pragma unroll
  for (int s = 0; s < S_; ++s) {
    vA[s] = *(const u16x4*)&xt[ia[s] * C_ + 4 * q];
    vB[s] = *(const u16x4*)&xt[ib[s] * C_ + 4 * q];
  }
  __builtin_amdgcn_sched_barrier(0);

  f32x4 sd = {0,0,0,0}, qd = {0,0,0,0}, sc = {0,0,0,0}, qc = {0,0,0,0};
  float cenA[4], cenB[4];
#pragma unroll
  for (int i = 0; i < 4; ++i) {
    cenA[i] = bf2f(cA[i]); cenB[i] = bf2f(cB[i]);
    sc[i] += cenA[i] + cenB[i];
    qc[i] += cenA[i] * cenA[i] + cenB[i] * cenB[i];
  }
#pragma unroll
  for (int s = 0; s < S_; ++s) {
#pragma unroll
    for (int i = 0; i < 4; ++i) {
      const float dA = bf2f(vA[s][i]) - cenA[i];
      const float dB = bf2f(vB[s][i]) - cenB[i];
      sd[i] += dA + dB;
      qd[i] += dA * dA + dB * dB;
    }
  }

#pragma unroll
  for (int i = 0; i < 4; ++i) {
    sd[i] += __shfl_xor(sd[i], 16); sd[i] += __shfl_xor(sd[i], 32);
    qd[i] += __shfl_xor(qd[i], 16); qd[i] += __shfl_xor(qd[i], 32);
    sc[i] += __shfl_xor(sc[i], 16); sc[i] += __shfl_xor(sc[i], 32);
    qc[i] += __shfl_xor(qc[i], 16); qc[i] += __shfl_xor(qc[i], 32);
  }

  __shared__ float sred[4][4][64];
  if (lane < 16) {
    *(f32x4*)&sred[0][w][4 * q] = sd;
    *(f32x4*)&sred[1][w][4 * q] = qd;
    *(f32x4*)&sred[2][w][4 * q] = sc;
    *(f32x4*)&sred[3][w][4 * q] = qc;
  }
  __syncthreads();
  if (t < 64) {
    float* dst = statsR + (blockIdx.x & (RST_ - 1)) * 256;
#pragma unroll
    for (int k = 0; k < 4; ++k) {
      const float v = sred[k][0][t] + sred[k][1][t] + sred[k][2][t] + sred[k][3][t];
      atomicAdd(&dst[k * 64 + t], v);
    }
  }
}

// ---------------- fold: replica-sum + BN fold -> AB[256] ----------------
__global__ void k_fold(const float* __restrict__ statsR, const float* __restrict__ dww,
                       const float* __restrict__ gamma, const float* __restrict__ beta,
                       float* __restrict__ AB) {
  __shared__ float sstat[256];
  const int t = threadIdx.x;   // 256 threads
  float sv = 0.f;
#pragma unroll
  for (int rr = 0; rr < RST_; ++rr) sv += statsR[rr * 256 + t];
  sstat[t] = sv;
  __syncthreads();
  if (t < CH_) {
    float mean_e, var_e;
    if (t < C_) {
      const float cnt = (float)ROWS_ * (float)S_;
      mean_e = sstat[t] / cnt; var_e = sstat[64 + t] / cnt - mean_e * mean_e;
    } else {
      const float cnt = (float)ROWS_;
      mean_e = sstat[128 + (t - C_)] / cnt; var_e = sstat[192 + (t - C_)] / cnt - mean_e * mean_e;
    }
    const float wg = dww[t], g = gamma[t];
    const float inv = rsqrtf(wg * wg * var_e + 1e-5f);
    AB[t]       = wg * g * inv;
    AB[CH_ + t] = beta[t] - wg * mean_e * inv * g;
  }
}

// ---------------- main: LDS-free, xt-gather, inline affine, 3-phase registers ----------------
__global__ __launch_bounds__(256, 3) void k_main(
    const __bf16* __restrict__ xt, const int* __restrict__ sampled,
    const float* __restrict__ AB, const __bf16* __restrict__ pwb2,
    float* __restrict__ out) {
  const int t   = threadIdx.x;
  const int l   = t & 63;
  const int w   = t >> 6;
  const int j0  = blockIdx.x * 64 + w * 16;     // wave's 16-row group
  const int b   = j0 / N_;
  const int n0  = j0 % N_;
  const int col = l & 15;                        // A row / D col
  const int ks  = l >> 4;                        // k-slice 0..3
  const int jr  = j0 + col;                      // this lane's data row
  const int cb  = 8 * ks;                        // channel base

  // ---- phase 1: issue all loads ----
  int nb[S_];
  const int* sp = sampled + (size_t)jr * S_;
#pragma unroll
  for (int s = 0; s < S_; ++s) nb[s] = sp[s];

  u16x8 vd[S_][2];
#pragma unroll
  for (int s = 0; s < S_; ++s) {
    const __bf16* p = xt + (size_t)nb[s] * C_ + cb;
    vd[s][0] = *(const u16x8*)p;
    vd[s][1] = *(const u16x8*)(p + 32);
  }
  u16x8 cd0 = *(const u16x8*)(xt + (size_t)jr * C_ + cb);
  u16x8 cd1 = *(const u16x8*)(xt + (size_t)jr * C_ + cb + 32);

  f32x4 ad0a = *(const f32x4*)&AB[cb];            f32x4 ad0b = *(const f32x4*)&AB[cb + 4];
  f32x4 ad1a = *(const f32x4*)&AB[32 + cb];       f32x4 ad1b = *(const f32x4*)&AB[32 + cb + 4];
  f32x4 bd0a = *(const f32x4*)&AB[CH_ + cb];      f32x4 bd0b = *(const f32x4*)&AB[CH_ + cb + 4];
  f32x4 bd1a = *(const f32x4*)&AB[CH_ + 32 + cb]; f32x4 bd1b = *(const f32x4*)&AB[CH_ + 32 + cb + 4];
  __builtin_amdgcn_sched_barrier(0);

  // ---- phase 2: act in registers ----
  // cc = A_d*cen - B_d ; act_d = leaky(A_d*v - cc) ; act_c = leaky(A_c*cen + B_c)
  float ad[16], cc[16], cen[16];
#pragma unroll
  for (int i = 0; i < 4; ++i) {
    ad[i]      = ad0a[i]; ad[4 + i]  = ad0b[i];
    ad[8 + i]  = ad1a[i]; ad[12 + i] = ad1b[i];
    cen[i]      = bf2f(cd0[i]);     cen[4 + i]  = bf2f(cd0[4 + i]);
    cen[8 + i]  = bf2f(cd1[i]);     cen[12 + i] = bf2f(cd1[4 + i]);
    cc[i]      = ad[i]      * cen[i]      - bd0a[i];
    cc[4 + i]  = ad[4 + i]  * cen[4 + i]  - bd0b[i];
    cc[8 + i]  = ad[8 + i]  * cen[8 + i]  - bd1a[i];
    cc[12 + i] = ad[12 + i] * cen[12 + i] - bd1b[i];
  }

  bf16x8 pa[S_][2];
#pragma unroll
  for (int s = 0; s < S_; ++s) {
#pragma unroll
    for (int i = 0; i < 8; ++i) {
      const float z0 = ad[i] * bf2f(vd[s][0][i]) - cc[i];
      pa[s][0][i] = (__bf16)fmaxf(z0, 0.2f * z0);
      const float z1 = ad[8 + i] * bf2f(vd[s][1][i]) - cc[8 + i];
      pa[s][1][i] = (__bf16)fmaxf(z1, 0.2f * z1);
    }
  }

  bf16x8 pc[2];
  {
    f32x4 ac0a = *(const f32x4*)&AB[C_ + cb];            f32x4 ac0b = *(const f32x4*)&AB[C_ + cb + 4];
    f32x4 ac1a = *(const f32x4*)&AB[C_ + 32 + cb];       f32x4 ac1b = *(const f32x4*)&AB[C_ + 32 + cb + 4];
    f32x4 bc0a = *(const f32x4*)&AB[CH_ + C_ + cb];      f32x4 bc0b = *(const f32x4*)&AB[CH_ + C_ + cb + 4];
    f32x4 bc1a = *(const f32x4*)&AB[CH_ + C_ + 32 + cb]; f32x4 bc1b = *(const f32x4*)&AB[CH_ + C_ + 32 + cb + 4];
#pragma unroll
    for (int i = 0; i < 4; ++i) {
      float z;
      z = ac0a[i] * cen[i]      + bc0a[i]; pc[0][i]     = (__bf16)fmaxf(z, 0.2f * z);
      z = ac0b[i] * cen[4 + i]  + bc0b[i]; pc[0][4 + i] = (__bf16)fmaxf(z, 0.2f * z);
      z = ac1a[i] * cen[8 + i]  + bc1a[i]; pc[1][i]     = (__bf16)fmaxf(z, 0.2f * z);
      z = ac1b[i] * cen[12 + i] + bc1b[i]; pc[1][4 + i] = (__bf16)fmaxf(z, 0.2f * z);
    }
  }
  __builtin_amdgcn_sched_barrier(0);

  // ---- phase 3: MFMA per output group, store directly ----
#pragma unroll
  for (int og = 0; og < 4; ++og) {
    const int fb = ((og * 2 + 0) * 4 + ks) * 16 + col;
    const int fb1 = ((og * 2 + 1) * 4 + ks) * 16 + col;
    bf16x8 wd0 = *(const bf16x8*)&pwb2[fb * 8];
    bf16x8 wd1 = *(const bf16x8*)&pwb2[fb1 * 8];
    bf16x8 wc0 = *(const bf16x8*)&pwb2[4096 + fb * 8];
    bf16x8 wc1 = *(const bf16x8*)&pwb2[4096 + fb1 * 8];

    f32x4 rmax;
    rmax[0] = rmax[1] = rmax[2] = rmax[3] = -__builtin_inff();
#pragma unroll
    for (int s = 0; s < S_; ++s) {
      f32x4 acc = {0.f, 0.f, 0.f, 0.f};
      acc = __builtin_amdgcn_mfma_f32_16x16x32_bf16(pa[s][0], wd0, acc, 0, 0, 0);
      acc = __builtin_amdgcn_mfma_f32_16x16x32_bf16(pa[s][1], wd1, acc, 0, 0, 0);
#pragma unroll
      for (int i = 0; i < 4; ++i) rmax[i] = fmaxf(rmax[i], acc[i]);
    }
    f32x4 cacc = {0.f, 0.f, 0.f, 0.f};
    cacc = __builtin_amdgcn_mfma_f32_16x16x32_bf16(pc[0], wc0, cacc, 0, 0, 0);
    cacc = __builtin_amdgcn_mfma_f32_16x16x32_bf16(pc[1], wc1, cacc, 0, 0, 0);
    f32x4 v;
#pragma unroll
    for (int i = 0; i < 4; ++i) v[i] = rmax[i] + cacc[i];
    // D layout: col = out channel 16og+col, rows = n0 + 4ks + i (contiguous in N)
    *(f32x4*)&out[(size_t)(b * OUT_ + 16 * og + col) * N_ + n0 + 4 * ks] = v;
  }
}

extern "C" void kernel_launch(void* const* d_in, const int* in_sizes, int n_in,
                              void* d_out, int out_size, void* d_ws, size_t ws_size,
                              hipStream_t stream) {
  const float* x      = (const float*)d_in[0];
  const int*   cif    = (const int*)  d_in[1];
  const float* scores = (const float*)d_in[2];
  const float* dww    = (const float*)d_in[3];
  const float* pw     = (const float*)d_in[4];
  const float* gamma  = (const float*)d_in[5];
  const float* beta   = (const float*)d_in[6];
  float* out = (float*)d_out;

  char* ws = (char*)d_ws;
  __bf16* xt      = (__bf16*)(ws);                    //  8,388,608 B
  int*    sampled = (int*)   (ws + 8388608);          //  2,621,440 B
  float*  statsR  = (float*) (ws + 11010048);         //     16,384 B
  float*  AB      = (float*) (ws + 11026432);         //      1,024 B
  __bf16* pwb2    = (__bf16*)(ws + 11027456);         //     16,384 B

  k_prep<<<4096 + 256 + 1, 256, 0, stream>>>(x, xt, scores, cif, sampled, statsR, pw, pwb2);
  k_stats<<<ROWS_ / 32, 256, 0, stream>>>(xt, sampled, statsR);
  k_fold<<<1, 256, 0, stream>>>(statsR, dww, gamma, beta, AB);
  k_main<<<ROWS_ / 64, 256, 0, stream>>>(xt, sampled, AB, pwb2, out);
}

// Round 12
// 51.381 us; speedup vs baseline: 1.2286x; 1.1592x over previous
//
#include <hip/hip_runtime.h>
#include <hip/hip_bf16.h>

#define B_   4
#define C_   64
#define N_   16384
#define K_   20
#define S_   10
#define OUT_ 64
#define CH_  128
#define ROWS_ (B_ * N_)
#define RST_ 16      // stats replicas
#define SUBB_ 512    // stats blocks; d-stats rows = 4*(bid*32 + r)  (1/4 subsample)
#define DCNT_ (16384.0f * 10.0f)

typedef __attribute__((ext_vector_type(4))) float  f32x4;
typedef __attribute__((ext_vector_type(8))) __bf16 bf16x8;
typedef __attribute__((ext_vector_type(4))) __bf16 bf16x4;
typedef __attribute__((ext_vector_type(4))) unsigned short u16x4;
typedef __attribute__((ext_vector_type(8))) unsigned short u16x8;

__device__ inline float bf2f(unsigned short u) {
  union { unsigned int i; float f; } x; x.i = ((unsigned int)u) << 16; return x.f;
}

// ---- fused: transpose -> bf16 xt | top-S sample | statsR zero | pw bf16 prepack ----
__global__ __launch_bounds__(256) void k_prep(
    const float* __restrict__ x, __bf16* __restrict__ xt,
    const float* __restrict__ scores, const int* __restrict__ idxmat,
    int* __restrict__ sampled, float* __restrict__ statsR,
    const float* __restrict__ pw, __bf16* __restrict__ pwb) {
  const int bid = blockIdx.x;
  const int t   = threadIdx.x;
  if (bid < 4096) {
    __shared__ float tile[32][33];   // [c_local][n_local]
    const int nt = bid & 511, ct = (bid >> 9) & 1, b = bid >> 10;
    const int n0 = nt * 32, c0 = ct * 32;
    const int tx = t & 31, ty = t >> 5;
#pragma unroll
    for (int k = 0; k < 32; k += 8)
      tile[ty + k][tx] = x[((size_t)(b * C_ + c0 + ty + k)) * N_ + n0 + tx];
    __syncthreads();
    const int nl = t >> 3;           // 0..31 (n)
    const int cb = (t & 7) * 4;      // 0..28 (c)
    bf16x4 p;
#pragma unroll
    for (int i = 0; i < 4; ++i) p[i] = (__bf16)tile[cb + i][nl];
    *(bf16x4*)&xt[((size_t)(b * N_ + n0 + nl)) * C_ + c0 + cb] = p;
  } else if (bid < 4352) {
    if (bid == 4096) {
#pragma unroll
      for (int i = 0; i < RST_; ++i) statsR[i * 256 + t] = 0.f;
    }
    const int j = (bid - 4096) * 256 + t;
    const float* sc = scores + (size_t)j * K_;
    const int*   id = idxmat + (size_t)j * K_;
    float sv[K_]; int iv[K_];
#pragma unroll
    for (int k = 0; k < K_; ++k) { sv[k] = sc[k]; iv[k] = id[k]; }
    int* outp = sampled + (size_t)j * S_;
#pragma unroll
    for (int k = 0; k < K_; ++k) {
      const float sk = sv[k];
      int rank = 0;
#pragma unroll
      for (int m = 0; m < K_; ++m)
        rank += ((sv[m] > sk) || (sv[m] == sk && m < k)) ? 1 : 0;
      if (rank < S_) outp[rank] = iv[k];
    }
  } else {
    // pack pw (OUT,2C) f32 -> per-thread bf16 fragments [256][32]
    const int o  = 16 * (t >> 6) + (t & 15);
    const int kb = 8 * ((t >> 4) & 3);
    const float* src = pw + (size_t)o * CH_;
    __bf16* dst = pwb + t * 32;
#pragma unroll
    for (int ts = 0; ts < 2; ++ts)
#pragma unroll
      for (int i = 0; i < 8; ++i) {
        dst[ts * 8 + i]      = (__bf16)src[32 * ts + kb + i];        // d-part
        dst[16 + ts * 8 + i] = (__bf16)src[C_ + 32 * ts + kb + i];   // c-part
      }
  }
}

// ---------------- BN stats: 1/4-subsampled d-stats + exact dense c-stats ----------------
// statsR[rep][0:64)=sum_d [64:128)=sumsq_d [128:192)=sum_cen [192:256)=sumsq_cen
__global__ __launch_bounds__(256, 4) void k_stats(const __bf16* __restrict__ xt,
                                                  const int* __restrict__ sampled,
                                                  float* __restrict__ statsR) {
  const int t    = threadIdx.x;
  const int lane = t & 63;
  const int w    = t >> 6;
  const int r    = t >> 4;
  const int q    = t & 15;
  const int j0   = blockIdx.x * 32;
  const int jA   = 4 * (j0 + r);          // strided subsample rows
  const int jB   = 4 * (j0 + 16 + r);

  // --- issue all loads ---
  int ia[S_], ib[S_];
  const int* spA = sampled + (size_t)jA * S_;
  const int* spB = sampled + (size_t)jB * S_;
#pragma unroll
  for (int s = 0; s < S_; ++s) { ia[s] = spA[s]; ib[s] = spB[s]; }

  u16x4 cA = *(const u16x4*)&xt[jA * C_ + 4 * q];
  u16x4 cB = *(const u16x4*)&xt[jB * C_ + 4 * q];

  u16x4 vA[S_], vB[S_];
#pragma unroll
  for (int s = 0; s < S_; ++s) {
    vA[s] = *(const u16x4*)&xt[ia[s] * C_ + 4 * q];
    vB[s] = *(const u16x4*)&xt[ib[s] * C_ + 4 * q];
  }

  // dense c-stats: block covers rows [bid*128, bid*128+128), fully coalesced
  u16x8 cv[4];
  {
    const int rbase = blockIdx.x * 128 + (t >> 3);
    const int c8 = (t & 7) * 8;
#pragma unroll
    for (int it = 0; it < 4; ++it)
      cv[it] = *(const u16x8*)&xt[(size_t)(rbase + it * 32) * C_ + c8];
  }
  __builtin_amdgcn_sched_barrier(0);

  // --- d-part compute ---
  f32x4 sd = {0,0,0,0}, qd = {0,0,0,0};
  float cenA[4], cenB[4];
#pragma unroll
  for (int i = 0; i < 4; ++i) { cenA[i] = bf2f(cA[i]); cenB[i] = bf2f(cB[i]); }
#pragma unroll
  for (int s = 0; s < S_; ++s) {
#pragma unroll
    for (int i = 0; i < 4; ++i) {
      const float dA = bf2f(vA[s][i]) - cenA[i];
      const float dB = bf2f(vB[s][i]) - cenB[i];
      sd[i] += dA + dB;
      qd[i] += dA * dA + dB * dB;
    }
  }

  // --- c-part compute ---
  float sc8[8] = {0,0,0,0,0,0,0,0}, qc8[8] = {0,0,0,0,0,0,0,0};
#pragma unroll
  for (int it = 0; it < 4; ++it)
#pragma unroll
    for (int i = 0; i < 8; ++i) {
      const float f = bf2f(cv[it][i]);
      sc8[i] += f; qc8[i] += f * f;
    }

  // --- reduce d across r (lanes differing in bits 4,5 share q) ---
#pragma unroll
  for (int i = 0; i < 4; ++i) {
    sd[i] += __shfl_xor(sd[i], 16); sd[i] += __shfl_xor(sd[i], 32);
    qd[i] += __shfl_xor(qd[i], 16); qd[i] += __shfl_xor(qd[i], 32);
  }
  // --- reduce c across lanes sharing (lane&7) ---
#pragma unroll
  for (int i = 0; i < 8; ++i) {
    sc8[i] += __shfl_xor(sc8[i], 8);  qc8[i] += __shfl_xor(qc8[i], 8);
    sc8[i] += __shfl_xor(sc8[i], 16); qc8[i] += __shfl_xor(qc8[i], 16);
    sc8[i] += __shfl_xor(sc8[i], 32); qc8[i] += __shfl_xor(qc8[i], 32);
  }

  __shared__ float sredD[2][4][64];   // [stat][wave][channel]
  __shared__ float sredC[4][128];     // [wave][sum 0..63 | sq 64..127]
  if (lane < 16) {
    *(f32x4*)&sredD[0][w][4 * q] = sd;
    *(f32x4*)&sredD[1][w][4 * q] = qd;
  }
  if (lane < 8) {
#pragma unroll
    for (int i = 0; i < 8; ++i) {
      sredC[w][lane * 8 + i]      = sc8[i];
      sredC[w][64 + lane * 8 + i] = qc8[i];
    }
  }
  __syncthreads();
  if (t < 64) {
    float* dst = statsR + (blockIdx.x & (RST_ - 1)) * 256;
    atomicAdd(&dst[t],       sredD[0][0][t] + sredD[0][1][t] + sredD[0][2][t] + sredD[0][3][t]);
    atomicAdd(&dst[64 + t],  sredD[1][0][t] + sredD[1][1][t] + sredD[1][2][t] + sredD[1][3][t]);
    atomicAdd(&dst[128 + t], sredC[0][t] + sredC[1][t] + sredC[2][t] + sredC[3][t]);
    atomicAdd(&dst[192 + t], sredC[0][64 + t] + sredC[1][64 + t] + sredC[2][64 + t] + sredC[3][64 + t]);
  }
}

// ---------------- main: 32 rows/block, inline fold, dual-tile LDS MFMA ----------------
__global__ __launch_bounds__(256, 4) void k_main(
    const __bf16* __restrict__ xt, const int* __restrict__ sampled,
    const float* __restrict__ statsR, const float* __restrict__ dww,
    const float* __restrict__ gamma, const float* __restrict__ beta,
    const __bf16* __restrict__ pwb, float* __restrict__ out) {
  __shared__ __bf16 dact[160 * 64];   // 20480 B; rows (s*16+r), 128B each, XOR-swizzled
  __shared__ __bf16 cact[16 * 64];    //  2048 B
  __shared__ float  ABs[256];
  __shared__ float  sstat[256];
  float* ost = (float*)dact;          // epilogue alias (dact dead by then)

  const int t    = threadIdx.x;
  const int lane = t & 63;
  const int w    = t >> 6;            // wave -> output cols [16w,16w+16)
  const int j0   = blockIdx.x * 32;
  const int b    = j0 / N_;
  const int n0   = j0 % N_;
  const int r    = t >> 4;            // row 0..15 within tile
  const int q    = t & 15;            // channel quad
  const int jA   = j0 + r;
  const int jB   = j0 + 16 + r;

  // ---- load phase: everything in flight before any compute ----
  int ia[S_], ib[S_];
  const int* spA = sampled + (size_t)jA * S_;
  const int* spB = sampled + (size_t)jB * S_;
#pragma unroll
  for (int s = 0; s < S_; ++s) { ia[s] = spA[s]; ib[s] = spB[s]; }

  u16x4 cuA = *(const u16x4*)&xt[jA * C_ + 4 * q];
  u16x4 cuB = *(const u16x4*)&xt[jB * C_ + 4 * q];

  u16x4 vuA[S_], vuB[S_];
#pragma unroll
  for (int s = 0; s < S_; ++s) {
    vuA[s] = *(const u16x4*)&xt[ia[s] * C_ + 4 * q];
    vuB[s] = *(const u16x4*)&xt[ib[s] * C_ + 4 * q];
  }

  bf16x8 bfd[2], bfc[2];
  {
    const bf16x8* fp = (const bf16x8*)(pwb + t * 32);
    bfd[0] = fp[0]; bfd[1] = fp[1]; bfc[0] = fp[2]; bfc[1] = fp[3];
  }
  __builtin_amdgcn_sched_barrier(0);

  // ---- inline BN fold (redundant per block) ----
  {
    float sv = 0.f;
#pragma unroll
    for (int rr = 0; rr < RST_; ++rr) sv += statsR[rr * 256 + t];
    sstat[t] = sv;
    __syncthreads();
    if (t < CH_) {
      float mean_e, var_e;
      if (t < C_) {
        mean_e = sstat[t] / DCNT_;
        var_e  = sstat[64 + t] / DCNT_ - mean_e * mean_e;
      } else {
        const float cnt = (float)ROWS_;
        mean_e = sstat[128 + (t - C_)] / cnt;
        var_e  = sstat[192 + (t - C_)] / cnt - mean_e * mean_e;
      }
      const float wg = dww[t], g = gamma[t];
      const float inv = rsqrtf(wg * wg * var_e + 1e-5f);
      ABs[t]       = wg * g * inv;
      ABs[CH_ + t] = beta[t] - wg * mean_e * inv * g;
    }
    __syncthreads();
  }

  const f32x4 a_d = *(const f32x4*)&ABs[4 * q];
  const f32x4 a_c = *(const f32x4*)&ABs[C_ + 4 * q];
  const f32x4 b_d = *(const f32x4*)&ABs[CH_ + 4 * q];
  const f32x4 b_c = *(const f32x4*)&ABs[CH_ + C_ + 4 * q];

  const int wbyt  = r * 128 + ((8 * q) ^ ((r & 7) << 4));   // act write offset (row r)
  const int arow  = lane & 15;
  const int akoff = 16 * (lane >> 4);
  const int swz   = (arow & 7) << 4;

  // ================= tile A =================
  float cen[4];
  {
    bf16x4 p;
#pragma unroll
    for (int i = 0; i < 4; ++i) {
      cen[i] = bf2f(cuA[i]);
      const float tt = a_c[i] * cen[i] + b_c[i];
      p[i] = (__bf16)fmaxf(tt, 0.2f * tt);
    }
    *(bf16x4*)((char*)cact + wbyt) = p;
  }
#pragma unroll
  for (int s = 0; s < S_; ++s) {
    bf16x4 p;
#pragma unroll
    for (int i = 0; i < 4; ++i) {
      const float d  = bf2f(vuA[s][i]) - cen[i];
      const float tt = a_d[i] * d + b_d[i];
      p[i] = (__bf16)fmaxf(tt, 0.2f * tt);
    }
    *(bf16x4*)((char*)dact + s * 2048 + wbyt) = p;   // row s*16+r; (row&7)==(r&7)
  }
  __syncthreads();

  f32x4 caccA = {0.f, 0.f, 0.f, 0.f};
#pragma unroll
  for (int ts = 0; ts < 2; ++ts) {
    bf16x8 a = *(bf16x8*)((char*)cact + arow * 128 + ((64 * ts + akoff) ^ swz));
    caccA = __builtin_amdgcn_mfma_f32_16x16x32_bf16(a, bfc[ts], caccA, 0, 0, 0);
  }
  f32x4 rmaxA;
  rmaxA[0] = rmaxA[1] = rmaxA[2] = rmaxA[3] = -__builtin_inff();
#pragma unroll
  for (int s = 0; s < S_; ++s) {
    f32x4 acc = {0.f, 0.f, 0.f, 0.f};
#pragma unroll
    for (int ts = 0; ts < 2; ++ts) {
      bf16x8 a = *(bf16x8*)((char*)dact + s * 2048 + arow * 128 + ((64 * ts + akoff) ^ swz));
      acc = __builtin_amdgcn_mfma_f32_16x16x32_bf16(a, bfd[ts], acc, 0, 0, 0);
    }
#pragma unroll
    for (int i = 0; i < 4; ++i) rmaxA[i] = fmaxf(rmaxA[i], acc[i]);
  }
  __syncthreads();   // tile-A LDS consumed

  // ================= tile B =================
  {
    bf16x4 p;
#pragma unroll
    for (int i = 0; i < 4; ++i) {
      cen[i] = bf2f(cuB[i]);
      const float tt = a_c[i] * cen[i] + b_c[i];
      p[i] = (__bf16)fmaxf(tt, 0.2f * tt);
    }
    *(bf16x4*)((char*)cact + wbyt) = p;
  }
#pragma unroll
  for (int s = 0; s < S_; ++s) {
    bf16x4 p;
#pragma unroll
    for (int i = 0; i < 4; ++i) {
      const float d  = bf2f(vuB[s][i]) - cen[i];
      const float tt = a_d[i] * d + b_d[i];
      p[i] = (__bf16)fmaxf(tt, 0.2f * tt);
    }
    *(bf16x4*)((char*)dact + s * 2048 + wbyt) = p;
  }
  __syncthreads();

  f32x4 caccB = {0.f, 0.f, 0.f, 0.f};
#pragma unroll
  for (int ts = 0; ts < 2; ++ts) {
    bf16x8 a = *(bf16x8*)((char*)cact + arow * 128 + ((64 * ts + akoff) ^ swz));
    caccB = __builtin_amdgcn_mfma_f32_16x16x32_bf16(a, bfc[ts], caccB, 0, 0, 0);
  }
  f32x4 rmaxB;
  rmaxB[0] = rmaxB[1] = rmaxB[2] = rmaxB[3] = -__builtin_inff();
#pragma unroll
  for (int s = 0; s < S_; ++s) {
    f32x4 acc = {0.f, 0.f, 0.f, 0.f};
#pragma unroll
    for (int ts = 0; ts < 2; ++ts) {
      bf16x8 a = *(bf16x8*)((char*)dact + s * 2048 + arow * 128 + ((64 * ts + akoff) ^ swz));
      acc = __builtin_amdgcn_mfma_f32_16x16x32_bf16(a, bfd[ts], acc, 0, 0, 0);
    }
#pragma unroll
    for (int i = 0; i < 4; ++i) rmaxB[i] = fmaxf(rmaxB[i], acc[i]);
  }
  __syncthreads();   // dact fully dead; reuse as ost[32][68]

  // ---- epilogue: stage both tiles, store 128B runs per o-row ----
  {
    const int ol = lane & 15;
    const int rb = 4 * (lane >> 4);
#pragma unroll
    for (int i = 0; i < 4; ++i) {
      ost[(rb + i) * 68 + 16 * w + ol]      = rmaxA[i] + caccA[i];
      ost[(16 + rb + i) * 68 + 16 * w + ol] = rmaxB[i] + caccB[i];
    }
  }
  __syncthreads();
  {
    const int o  = t >> 2;
    const int sg = t & 3;
    f32x4 vA, vB;
#pragma unroll
    for (int i = 0; i < 4; ++i) {
      vA[i] = ost[(sg * 4 + i) * 68 + o];
      vB[i] = ost[(16 + sg * 4 + i) * 68 + o];
    }
    float* op = &out[((size_t)(b * OUT_ + o)) * N_ + n0];
    *(f32x4*)(op + sg * 4)      = vA;
    *(f32x4*)(op + 16 + sg * 4) = vB;
  }
}

extern "C" void kernel_launch(void* const* d_in, const int* in_sizes, int n_in,
                              void* d_out, int out_size, void* d_ws, size_t ws_size,
                              hipStream_t stream) {
  const float* x      = (const float*)d_in[0];
  const int*   cif    = (const int*)  d_in[1];
  const float* scores = (const float*)d_in[2];
  const float* dww    = (const float*)d_in[3];
  const float* pw     = (const float*)d_in[4];
  const float* gamma  = (const float*)d_in[5];
  const float* beta   = (const float*)d_in[6];
  float* out = (float*)d_out;

  char* ws = (char*)d_ws;
  __bf16* xt      = (__bf16*)(ws);                                  //  8,388,608 B
  int*    sampled = (int*)   (ws + 8388608);                        //  2,621,440 B
  float*  statsR  = (float*) (ws + 8388608 + 2621440);              //     16,384 B
  __bf16* pwb     = (__bf16*)(ws + 8388608 + 2621440 + 16384);      //     16,384 B

  k_prep<<<4096 + 256 + 1, 256, 0, stream>>>(x, xt, scores, cif, sampled, statsR, pw, pwb);
  k_stats<<<SUBB_, 256, 0, stream>>>(xt, sampled, statsR);
  k_main<<<ROWS_ / 32, 256, 0, stream>>>(xt, sampled, statsR, dww, gamma, beta, pwb, out);
}

// Round 13
// 50.485 us; speedup vs baseline: 1.2504x; 1.0177x over previous
//
#include <hip/hip_runtime.h>
#include <hip/hip_bf16.h>

#define B_   4
#define C_   64
#define N_   16384
#define K_   20
#define S_   10
#define OUT_ 64
#define CH_  128
#define ROWS_ (B_ * N_)
#define RST_ 16      // stats replicas
#define SUBB_ 512    // stats blocks; d-stats rows = 4*(bid*32 + r)  (1/4 subsample)
#define DCNT_ (16384.0f * 10.0f)

typedef __attribute__((ext_vector_type(4))) float  f32x4;
typedef __attribute__((ext_vector_type(8))) __bf16 bf16x8;
typedef __attribute__((ext_vector_type(4))) __bf16 bf16x4;
typedef __attribute__((ext_vector_type(4))) unsigned short u16x4;
typedef __attribute__((ext_vector_type(8))) unsigned short u16x8;

__device__ inline float bf2f(unsigned short u) {
  union { unsigned int i; float f; } x; x.i = ((unsigned int)u) << 16; return x.f;
}

// ---- fused: transpose -> bf16 xt | top-S sample | statsR zero | pw bf16 prepack ----
__global__ __launch_bounds__(256) void k_prep(
    const float* __restrict__ x, __bf16* __restrict__ xt,
    const float* __restrict__ scores, const int* __restrict__ idxmat,
    int* __restrict__ sampled, float* __restrict__ statsR,
    const float* __restrict__ pw, __bf16* __restrict__ pwb) {
  const int bid = blockIdx.x;
  const int t   = threadIdx.x;
  if (bid < 4096) {
    __shared__ float tile[32][33];   // [c_local][n_local]
    const int nt = bid & 511, ct = (bid >> 9) & 1, b = bid >> 10;
    const int n0 = nt * 32, c0 = ct * 32;
    const int tx = t & 31, ty = t >> 5;
#pragma unroll
    for (int k = 0; k < 32; k += 8)
      tile[ty + k][tx] = x[((size_t)(b * C_ + c0 + ty + k)) * N_ + n0 + tx];
    __syncthreads();
    const int nl = t >> 3;           // 0..31 (n)
    const int cb = (t & 7) * 4;      // 0..28 (c)
    bf16x4 p;
#pragma unroll
    for (int i = 0; i < 4; ++i) p[i] = (__bf16)tile[cb + i][nl];
    *(bf16x4*)&xt[((size_t)(b * N_ + n0 + nl)) * C_ + c0 + cb] = p;
  } else if (bid < 4352) {
    if (bid == 4096) {
#pragma unroll
      for (int i = 0; i < RST_; ++i) statsR[i * 256 + t] = 0.f;
    }
    const int j = (bid - 4096) * 256 + t;
    const float* sc = scores + (size_t)j * K_;
    const int*   id = idxmat + (size_t)j * K_;
    float sv[K_]; int iv[K_];
#pragma unroll
    for (int k = 0; k < K_; ++k) { sv[k] = sc[k]; iv[k] = id[k]; }
    int* outp = sampled + (size_t)j * S_;
#pragma unroll
    for (int k = 0; k < K_; ++k) {
      const float sk = sv[k];
      int rank = 0;
#pragma unroll
      for (int m = 0; m < K_; ++m)
        rank += ((sv[m] > sk) || (sv[m] == sk && m < k)) ? 1 : 0;
      if (rank < S_) outp[rank] = iv[k];
    }
  } else {
    // pack pw (OUT,2C) f32 -> per-thread bf16 fragments [256][32]
    const int o  = 16 * (t >> 6) + (t & 15);
    const int kb = 8 * ((t >> 4) & 3);
    const float* src = pw + (size_t)o * CH_;
    __bf16* dst = pwb + t * 32;
#pragma unroll
    for (int ts = 0; ts < 2; ++ts)
#pragma unroll
      for (int i = 0; i < 8; ++i) {
        dst[ts * 8 + i]      = (__bf16)src[32 * ts + kb + i];        // d-part
        dst[16 + ts * 8 + i] = (__bf16)src[C_ + 32 * ts + kb + i];   // c-part
      }
  }
}

// ---------------- BN stats: 1/4-subsampled d-stats + exact dense c-stats ----------------
__global__ __launch_bounds__(256, 4) void k_stats(const __bf16* __restrict__ xt,
                                                  const int* __restrict__ sampled,
                                                  float* __restrict__ statsR) {
  const int t    = threadIdx.x;
  const int lane = t & 63;
  const int w    = t >> 6;
  const int r    = t >> 4;
  const int q    = t & 15;
  const int j0   = blockIdx.x * 32;
  const int jA   = 4 * (j0 + r);          // strided subsample rows
  const int jB   = 4 * (j0 + 16 + r);

  int ia[S_], ib[S_];
  const int* spA = sampled + (size_t)jA * S_;
  const int* spB = sampled + (size_t)jB * S_;
#pragma unroll
  for (int s = 0; s < S_; ++s) { ia[s] = spA[s]; ib[s] = spB[s]; }

  u16x4 cA = *(const u16x4*)&xt[jA * C_ + 4 * q];
  u16x4 cB = *(const u16x4*)&xt[jB * C_ + 4 * q];

  u16x4 vA[S_], vB[S_];
#pragma unroll
  for (int s = 0; s < S_; ++s) {
    vA[s] = *(const u16x4*)&xt[ia[s] * C_ + 4 * q];
    vB[s] = *(const u16x4*)&xt[ib[s] * C_ + 4 * q];
  }

  // dense c-stats: block covers rows [bid*128, bid*128+128)
  u16x8 cv[4];
  {
    const int rbase = blockIdx.x * 128 + (t >> 3);
    const int c8 = (t & 7) * 8;
#pragma unroll
    for (int it = 0; it < 4; ++it)
      cv[it] = *(const u16x8*)&xt[(size_t)(rbase + it * 32) * C_ + c8];
  }
  __builtin_amdgcn_sched_barrier(0);

  f32x4 sd = {0,0,0,0}, qd = {0,0,0,0};
  float cenA[4], cenB[4];
#pragma unroll
  for (int i = 0; i < 4; ++i) { cenA[i] = bf2f(cA[i]); cenB[i] = bf2f(cB[i]); }
#pragma unroll
  for (int s = 0; s < S_; ++s) {
#pragma unroll
    for (int i = 0; i < 4; ++i) {
      const float dA = bf2f(vA[s][i]) - cenA[i];
      const float dB = bf2f(vB[s][i]) - cenB[i];
      sd[i] += dA + dB;
      qd[i] += dA * dA + dB * dB;
    }
  }

  float sc8[8] = {0,0,0,0,0,0,0,0}, qc8[8] = {0,0,0,0,0,0,0,0};
#pragma unroll
  for (int it = 0; it < 4; ++it)
#pragma unroll
    for (int i = 0; i < 8; ++i) {
      const float f = bf2f(cv[it][i]);
      sc8[i] += f; qc8[i] += f * f;
    }

#pragma unroll
  for (int i = 0; i < 4; ++i) {
    sd[i] += __shfl_xor(sd[i], 16); sd[i] += __shfl_xor(sd[i], 32);
    qd[i] += __shfl_xor(qd[i], 16); qd[i] += __shfl_xor(qd[i], 32);
  }
#pragma unroll
  for (int i = 0; i < 8; ++i) {
    sc8[i] += __shfl_xor(sc8[i], 8);  qc8[i] += __shfl_xor(qc8[i], 8);
    sc8[i] += __shfl_xor(sc8[i], 16); qc8[i] += __shfl_xor(qc8[i], 16);
    sc8[i] += __shfl_xor(sc8[i], 32); qc8[i] += __shfl_xor(qc8[i], 32);
  }

  __shared__ float sredD[2][4][64];
  __shared__ float sredC[4][128];
  if (lane < 16) {
    *(f32x4*)&sredD[0][w][4 * q] = sd;
    *(f32x4*)&sredD[1][w][4 * q] = qd;
  }
  if (lane < 8) {
#pragma unroll
    for (int i = 0; i < 8; ++i) {
      sredC[w][lane * 8 + i]      = sc8[i];
      sredC[w][64 + lane * 8 + i] = qc8[i];
    }
  }
  __syncthreads();
  if (t < 64) {
    float* dst = statsR + (blockIdx.x & (RST_ - 1)) * 256;
    atomicAdd(&dst[t],       sredD[0][0][t] + sredD[0][1][t] + sredD[0][2][t] + sredD[0][3][t]);
    atomicAdd(&dst[64 + t],  sredD[1][0][t] + sredD[1][1][t] + sredD[1][2][t] + sredD[1][3][t]);
    atomicAdd(&dst[128 + t], sredC[0][t] + sredC[1][t] + sredC[2][t] + sredC[3][t]);
    atomicAdd(&dst[192 + t], sredC[0][64 + t] + sredC[1][64 + t] + sredC[2][64 + t] + sredC[3][64 + t]);
  }
}

// ---------------- main: 32 rows/block, PIPELINED tiles (one gather set live at a time) ----------------
__global__ __launch_bounds__(256, 4) void k_main(
    const __bf16* __restrict__ xt, const int* __restrict__ sampled,
    const float* __restrict__ statsR, const float* __restrict__ dww,
    const float* __restrict__ gamma, const float* __restrict__ beta,
    const __bf16* __restrict__ pwb, float* __restrict__ out) {
  __shared__ __bf16 dact[160 * 64];   // 20480 B; rows (s*16+r), 128B each, XOR-swizzled
  __shared__ __bf16 cact[16 * 64];    //  2048 B
  __shared__ float  ABs[256];
  __shared__ float  sstat[256];
  float* ost = (float*)dact;          // epilogue alias (dact dead by then)

  const int t    = threadIdx.x;
  const int lane = t & 63;
  const int w    = t >> 6;            // wave -> output cols [16w,16w+16)
  const int j0   = blockIdx.x * 32;
  const int b    = j0 / N_;
  const int n0   = j0 % N_;
  const int r    = t >> 4;            // row 0..15 within tile
  const int q    = t & 15;            // channel quad
  const int jA   = j0 + r;
  const int jB   = j0 + 16 + r;

  // ---- phase 1: indices + tile-A gathers + fragments (tile-B gathers NOT yet issued) ----
  int ia[S_], ib[S_];
  const int* spA = sampled + (size_t)jA * S_;
  const int* spB = sampled + (size_t)jB * S_;
#pragma unroll
  for (int s = 0; s < S_; ++s) { ia[s] = spA[s]; ib[s] = spB[s]; }

  u16x4 cuA = *(const u16x4*)&xt[jA * C_ + 4 * q];
  u16x4 vuA[S_];
#pragma unroll
  for (int s = 0; s < S_; ++s)
    vuA[s] = *(const u16x4*)&xt[ia[s] * C_ + 4 * q];

  bf16x8 bfd[2], bfc[2];
  {
    const bf16x8* fp = (const bf16x8*)(pwb + t * 32);
    bfd[0] = fp[0]; bfd[1] = fp[1]; bfc[0] = fp[2]; bfc[1] = fp[3];
  }
  __builtin_amdgcn_sched_barrier(0);

  // ---- inline BN fold (hides tile-A gather latency) ----
  {
    float sv = 0.f;
#pragma unroll
    for (int rr = 0; rr < RST_; ++rr) sv += statsR[rr * 256 + t];
    sstat[t] = sv;
    __syncthreads();
    if (t < CH_) {
      float mean_e, var_e;
      if (t < C_) {
        mean_e = sstat[t] / DCNT_;
        var_e  = sstat[64 + t] / DCNT_ - mean_e * mean_e;
      } else {
        const float cnt = (float)ROWS_;
        mean_e = sstat[128 + (t - C_)] / cnt;
        var_e  = sstat[192 + (t - C_)] / cnt - mean_e * mean_e;
      }
      const float wg = dww[t], g = gamma[t];
      const float inv = rsqrtf(wg * wg * var_e + 1e-5f);
      ABs[t]       = wg * g * inv;
      ABs[CH_ + t] = beta[t] - wg * mean_e * inv * g;
    }
    __syncthreads();
  }

  const f32x4 a_d = *(const f32x4*)&ABs[4 * q];
  const f32x4 a_c = *(const f32x4*)&ABs[C_ + 4 * q];
  const f32x4 b_d = *(const f32x4*)&ABs[CH_ + 4 * q];
  const f32x4 b_c = *(const f32x4*)&ABs[CH_ + C_ + 4 * q];

  const int wbyt  = r * 128 + ((8 * q) ^ ((r & 7) << 4));   // act write offset (row r)
  const int arow  = lane & 15;
  const int akoff = 16 * (lane >> 4);
  const int swz   = (arow & 7) << 4;

  // ---- act A -> LDS (vuA dies here) ----
  float cen[4];
  {
    bf16x4 p;
#pragma unroll
    for (int i = 0; i < 4; ++i) {
      cen[i] = bf2f(cuA[i]);
      const float tt = a_c[i] * cen[i] + b_c[i];
      p[i] = (__bf16)fmaxf(tt, 0.2f * tt);
    }
    *(bf16x4*)((char*)cact + wbyt) = p;
  }
#pragma unroll
  for (int s = 0; s < S_; ++s) {
    bf16x4 p;
#pragma unroll
    for (int i = 0; i < 4; ++i) {
      const float d  = bf2f(vuA[s][i]) - cen[i];
      const float tt = a_d[i] * d + b_d[i];
      p[i] = (__bf16)fmaxf(tt, 0.2f * tt);
    }
    *(bf16x4*)((char*)dact + s * 2048 + wbyt) = p;   // row s*16+r; (row&7)==(r&7)
  }

  // ---- issue tile-B gathers NOW (in flight during MFMA A) ----
  u16x4 cuB = *(const u16x4*)&xt[jB * C_ + 4 * q];
  u16x4 vuB[S_];
#pragma unroll
  for (int s = 0; s < S_; ++s)
    vuB[s] = *(const u16x4*)&xt[ib[s] * C_ + 4 * q];
  __builtin_amdgcn_sched_barrier(0);

  __syncthreads();

  // ---- MFMA A ----
  f32x4 caccA = {0.f, 0.f, 0.f, 0.f};
#pragma unroll
  for (int ts = 0; ts < 2; ++ts) {
    bf16x8 a = *(bf16x8*)((char*)cact + arow * 128 + ((64 * ts + akoff) ^ swz));
    caccA = __builtin_amdgcn_mfma_f32_16x16x32_bf16(a, bfc[ts], caccA, 0, 0, 0);
  }
  f32x4 rmaxA;
  rmaxA[0] = rmaxA[1] = rmaxA[2] = rmaxA[3] = -__builtin_inff();
#pragma unroll
  for (int s = 0; s < S_; ++s) {
    f32x4 acc = {0.f, 0.f, 0.f, 0.f};
#pragma unroll
    for (int ts = 0; ts < 2; ++ts) {
      bf16x8 a = *(bf16x8*)((char*)dact + s * 2048 + arow * 128 + ((64 * ts + akoff) ^ swz));
      acc = __builtin_amdgcn_mfma_f32_16x16x32_bf16(a, bfd[ts], acc, 0, 0, 0);
    }
#pragma unroll
    for (int i = 0; i < 4; ++i) rmaxA[i] = fmaxf(rmaxA[i], acc[i]);
  }
  __syncthreads();   // tile-A LDS consumed

  // ---- act B -> LDS ----
  {
    bf16x4 p;
#pragma unroll
    for (int i = 0; i < 4; ++i) {
      cen[i] = bf2f(cuB[i]);
      const float tt = a_c[i] * cen[i] + b_c[i];
      p[i] = (__bf16)fmaxf(tt, 0.2f * tt);
    }
    *(bf16x4*)((char*)cact + wbyt) = p;
  }
#pragma unroll
  for (int s = 0; s < S_; ++s) {
    bf16x4 p;
#pragma unroll
    for (int i = 0; i < 4; ++i) {
      const float d  = bf2f(vuB[s][i]) - cen[i];
      const float tt = a_d[i] * d + b_d[i];
      p[i] = (__bf16)fmaxf(tt, 0.2f * tt);
    }
    *(bf16x4*)((char*)dact + s * 2048 + wbyt) = p;
  }
  __syncthreads();

  // ---- MFMA B ----
  f32x4 caccB = {0.f, 0.f, 0.f, 0.f};
#pragma unroll
  for (int ts = 0; ts < 2; ++ts) {
    bf16x8 a = *(bf16x8*)((char*)cact + arow * 128 + ((64 * ts + akoff) ^ swz));
    caccB = __builtin_amdgcn_mfma_f32_16x16x32_bf16(a, bfc[ts], caccB, 0, 0, 0);
  }
  f32x4 rmaxB;
  rmaxB[0] = rmaxB[1] = rmaxB[2] = rmaxB[3] = -__builtin_inff();
#pragma unroll
  for (int s = 0; s < S_; ++s) {
    f32x4 acc = {0.f, 0.f, 0.f, 0.f};
#pragma unroll
    for (int ts = 0; ts < 2; ++ts) {
      bf16x8 a = *(bf16x8*)((char*)dact + s * 2048 + arow * 128 + ((64 * ts + akoff) ^ swz));
      acc = __builtin_amdgcn_mfma_f32_16x16x32_bf16(a, bfd[ts], acc, 0, 0, 0);
    }
#pragma unroll
    for (int i = 0; i < 4; ++i) rmaxB[i] = fmaxf(rmaxB[i], acc[i]);
  }
  __syncthreads();   // dact fully dead; reuse as ost[32][68]

  // ---- epilogue ----
  {
    const int ol = lane & 15;
    const int rb = 4 * (lane >> 4);
#pragma unroll
    for (int i = 0; i < 4; ++i) {
      ost[(rb + i) * 68 + 16 * w + ol]      = rmaxA[i] + caccA[i];
      ost[(16 + rb + i) * 68 + 16 * w + ol] = rmaxB[i] + caccB[i];
    }
  }
  __syncthreads();
  {
    const int o  = t >> 2;
    const int sg = t & 3;
    f32x4 vA, vB;
#pragma unroll
    for (int i = 0; i < 4; ++i) {
      vA[i] = ost[(sg * 4 + i) * 68 + o];
      vB[i] = ost[(16 + sg * 4 + i) * 68 + o];
    }
    float* op = &out[((size_t)(b * OUT_ + o)) * N_ + n0];
    *(f32x4*)(op + sg * 4)      = vA;
    *(f32x4*)(op + 16 + sg * 4) = vB;
  }
}

extern "C" void kernel_launch(void* const* d_in, const int* in_sizes, int n_in,
                              void* d_out, int out_size, void* d_ws, size_t ws_size,
                              hipStream_t stream) {
  const float* x      = (const float*)d_in[0];
  const int*   cif    = (const int*)  d_in[1];
  const float* scores = (const float*)d_in[2];
  const float* dww    = (const float*)d_in[3];
  const float* pw     = (const float*)d_in[4];
  const float* gamma  = (const float*)d_in[5];
  const float* beta   = (const float*)d_in[6];
  float* out = (float*)d_out;

  char* ws = (char*)d_ws;
  __bf16* xt      = (__bf16*)(ws);                                  //  8,388,608 B
  int*    sampled = (int*)   (ws + 8388608);                        //  2,621,440 B
  float*  statsR  = (float*) (ws + 8388608 + 2621440);              //     16,384 B
  __bf16* pwb     = (__bf16*)(ws + 8388608 + 2621440 + 16384);      //     16,384 B

  k_prep<<<4096 + 256 + 1, 256, 0, stream>>>(x, xt, scores, cif, sampled, statsR, pw, pwb);
  k_stats<<<SUBB_, 256, 0, stream>>>(xt, sampled, statsR);
  k_main<<<ROWS_ / 32, 256, 0, stream>>>(xt, sampled, statsR, dww, gamma, beta, pwb, out);
}